// Round 1
// baseline (18906.970 us; speedup 1.0000x reference)
//
#include <hip/hip_runtime.h>
#include <hip/hip_bf16.h>
#include <stdint.h>

typedef unsigned short ushort_t;
typedef unsigned int uint_t;
typedef __attribute__((ext_vector_type(8))) short short8;
typedef __attribute__((ext_vector_type(4))) float floatx4;

#define T_STEPS 2048
#define BATCH 16
#define IN_F 768
#define HID 512
#define G4 2048   // 4*HID
#define NBLK 32   // phase-2 blocks

// ---------------- workspace layout (bytes) ----------------
// xg   bf16 [T][16][2048]            : 134217728
// xT   bf16 [32768][768]             :  50331648
// wih  bf16 [2048][768]              :   3145728
// whh  bf16 [2048][512]              :   2097152
// hbuf bf16 [2][16][512]             :     32768
// cnt  u32                           :       256
static const size_t XG_OFF   = 0;
static const size_t XT_OFF   = 134217728ull;
static const size_t WIH_OFF  = XT_OFF + 50331648ull;
static const size_t WHH_OFF  = WIH_OFF + 3145728ull;
static const size_t HBUF_OFF = WHH_OFF + 2097152ull;
static const size_t CNT_OFF  = HBUF_OFF + 32768ull;
static const size_t WS_NEED  = CNT_OFF + 256ull;

// ---------------- helpers ----------------
__device__ inline ushort_t f2bf(float f) {
  uint_t u = __float_as_uint(f);
  u = (u + 0x7FFFu + ((u >> 16) & 1u)) >> 16;
  return (ushort_t)u;
}
__device__ inline float bf2f(ushort_t h) {
  return __uint_as_float(((uint_t)h) << 16);
}
__device__ inline floatx4 mfma16(short8 a, short8 b, floatx4 c) {
  return __builtin_amdgcn_mfma_f32_16x16x32_bf16(a, b, c, 0, 0, 0);
}
__device__ inline void ld_g2l16(const void* g, void* l) {
  __builtin_amdgcn_global_load_lds(
      (const __attribute__((address_space(1))) unsigned int*)g,
      (__attribute__((address_space(3))) unsigned int*)l, 16, 0, 0);
}
__device__ inline float sigf(float x) {
  float e = __expf(-x);
  return __fdividef(1.0f, 1.0f + e);
}
__device__ inline float tanhf_fast(float x) {
  x = fminf(fmaxf(x, -15.0f), 15.0f);
  float e = __expf(2.0f * x);
  return __fdividef(e - 1.0f, e + 1.0f);
}

// ---------------- phase 0: converts ----------------
// x [16][2048][768] fp32 -> xT bf16 rows r = t*16+b
__global__ __launch_bounds__(256) void conv_x_k(const float4* __restrict__ x,
                                                ushort_t* __restrict__ xT) {
  uint_t idx = blockIdx.x * 256u + threadIdx.x;  // < 6291456 exactly
  float4 v = x[idx];
  uint_t e = idx * 4u;
  uint_t k = e % 768u;
  uint_t rin = e / 768u;          // b*2048 + t
  uint_t b = rin >> 11, t = rin & 2047u;
  size_t o = (size_t)(t * 16u + b) * 768u + k;
  ushort4 r;
  r.x = f2bf(v.x); r.y = f2bf(v.y); r.z = f2bf(v.z); r.w = f2bf(v.w);
  *(ushort4*)(xT + o) = r;
}

__global__ __launch_bounds__(256) void conv_w_k(const float4* __restrict__ src,
                                                ushort_t* __restrict__ dst, uint_t n4) {
  uint_t idx = blockIdx.x * 256u + threadIdx.x;
  if (idx >= n4) return;
  float4 v = src[idx];
  ushort4 r;
  r.x = f2bf(v.x); r.y = f2bf(v.y); r.z = f2bf(v.z); r.w = f2bf(v.w);
  *(ushort4*)(dst + (size_t)idx * 4u) = r;
}

// ---------------- phase 1: xg = xT @ wih^T + bias, bf16 out ----------------
// 128x128 tile, BK=64, global_load_lds(16B) staging, XOR-swizzled LDS.
__global__ __launch_bounds__(256) void gemm_xg(const ushort_t* __restrict__ A,
                                               const ushort_t* __restrict__ Bw,
                                               const float* __restrict__ bih,
                                               const float* __restrict__ bhh,
                                               ushort_t* __restrict__ xg) {
  __shared__ __align__(16) ushort_t Asm[128 * 64];
  __shared__ __align__(16) ushort_t Bsm[128 * 64];
  const int tid = threadIdx.x;
  const int w = tid >> 6, l = tid & 63;
  const int m_ = l & 15, q = l >> 4;
  const int lr = l >> 3, lc = l & 7;
  const int nt = blockIdx.x, mt = blockIdx.y;
  const int wr = (w >> 1) * 64, wc = (w & 1) * 64;

  floatx4 acc[4][4];
  for (int i = 0; i < 4; i++)
    for (int j = 0; j < 4; j++) acc[i][j] = (floatx4){0.f, 0.f, 0.f, 0.f};

  for (int it = 0; it < 12; ++it) {
    const int K0 = it * 64;
    for (int p = 0; p < 4; p++) {
      int row = w * 32 + p * 8 + lr;      // tile row, (row&7)==lr
      int c = lc ^ lr;                    // swizzle: lane's stored slot lc holds global chunk c
      ld_g2l16(A + (size_t)(mt * 128 + row) * 768 + K0 + c * 8,
               Asm + (size_t)(w * 32 + p * 8) * 64);
      ld_g2l16(Bw + (size_t)(nt * 128 + row) * 768 + K0 + c * 8,
               Bsm + (size_t)(w * 32 + p * 8) * 64);
    }
    __syncthreads();
    short8 af[2][4], bfr[2][4];
    for (int kk = 0; kk < 2; kk++) {
      int chunk = kk * 4 + q;
      for (int rt = 0; rt < 4; rt++) {
        int row = wr + rt * 16 + m_;
        af[kk][rt] = *(const short8*)(Asm + (size_t)row * 64 + (size_t)(chunk ^ (row & 7)) * 8);
        int col = wc + rt * 16 + m_;
        bfr[kk][rt] = *(const short8*)(Bsm + (size_t)col * 64 + (size_t)(chunk ^ (col & 7)) * 8);
      }
    }
    for (int kk = 0; kk < 2; kk++)
      for (int rt = 0; rt < 4; rt++)
        for (int ct = 0; ct < 4; ct++)
          acc[rt][ct] = mfma16(af[kk][rt], bfr[kk][ct], acc[rt][ct]);
    __syncthreads();
  }
  // epilogue: C layout col=lane&15, row=quad*4+reg
  for (int ct = 0; ct < 4; ct++) {
    int gcol = nt * 128 + wc + ct * 16 + m_;
    float bias = bih[gcol] + bhh[gcol];
    for (int rt = 0; rt < 4; rt++) {
      int growb = mt * 128 + wr + rt * 16 + q * 4;
      for (int r = 0; r < 4; r++)
        xg[(size_t)(growb + r) * G4 + gcol] = f2bf(acc[rt][ct][r] + bias);
    }
  }
}

// ---------------- phase 2: persistent recurrent kernel ----------------
// 32 blocks x 256 threads. Block j owns h cols [16j,16j+16). Wave w = gate group w.
__global__ __launch_bounds__(256) void lstm_rec(const ushort_t* __restrict__ xg,
                                                const ushort_t* __restrict__ whh,
                                                ushort_t* hbuf, uint_t* cnt,
                                                float* __restrict__ out) {
  const int tid = threadIdx.x;
  const int w = tid >> 6, l = tid & 63;
  const int m_ = l & 15, q = l >> 4;
  const int j = blockIdx.x;
  const int gcolb = w * HID + j * 16;   // gate column base for this wave

  // pin w_hh slice in registers: B[k][n], lane n=m_, k=kk*32+q*8+jj
  short8 bfrag[16];
  {
    const ushort_t* wrow = whh + (size_t)(gcolb + m_) * HID + q * 8;
    for (int kk = 0; kk < 16; kk++) bfrag[kk] = *(const short8*)(wrow + kk * 32);
  }

  const int erow = tid >> 4, ecol = tid & 15;  // epilogue ownership (batch row, h col)
  float c_reg = 0.f;
  __shared__ float gsm[4][16][17];

  // xg frags for t=0 (C-layout init: reg r -> batch row q*4+r, col m_)
  ushort_t xgv[4];
  {
    const ushort_t* p = xg + (size_t)(q * 4) * G4 + gcolb + m_;
    for (int r = 0; r < 4; r++) xgv[r] = p[(size_t)r * G4];
  }

  for (int t = 0; t < T_STEPS; t++) {
    // prefetch next step's xg (independent of h)
    ushort_t xgn[4];
    {
      int tt = (t + 1 < T_STEPS) ? (t + 1) : t;
      const ushort_t* p = xg + ((size_t)tt * 16 + q * 4) * G4 + gcolb + m_;
      for (int r = 0; r < 4; r++) xgn[r] = p[(size_t)r * G4];
    }
    if (t > 0) {
      if (tid == 0) {
        while (__hip_atomic_load(cnt, __ATOMIC_RELAXED, __HIP_MEMORY_SCOPE_AGENT) <
               (uint_t)(NBLK * t)) {}
      }
      __syncthreads();
      __threadfence();  // acquire: invalidate caches so h reads are fresh
    }
    // A frags from h double buffer: A[m][k], lane m=m_, k=kk*32+q*8+jj
    const ushort_t* hb = hbuf + (size_t)(t & 1) * (BATCH * HID) + (size_t)m_ * HID + q * 8;
    short8 af[16];
    for (int kk = 0; kk < 16; kk++) af[kk] = *(const short8*)(hb + kk * 32);

    floatx4 acc0 = (floatx4){bf2f(xgv[0]), bf2f(xgv[1]), bf2f(xgv[2]), bf2f(xgv[3])};
    floatx4 acc1 = (floatx4){0.f, 0.f, 0.f, 0.f};
    for (int kk = 0; kk < 16; kk += 2) {
      acc0 = mfma16(af[kk], bfrag[kk], acc0);
      acc1 = mfma16(af[kk + 1], bfrag[kk + 1], acc1);
    }
    floatx4 acc = acc0 + acc1;

    for (int r = 0; r < 4; r++) gsm[w][q * 4 + r][m_] = acc[r];
    __syncthreads();

    float iv = sigf(gsm[0][erow][ecol]);
    float fv = sigf(gsm[1][erow][ecol]);
    float gv = tanhf_fast(gsm[2][erow][ecol]);
    float ov = sigf(gsm[3][erow][ecol]);
    float c = fv * c_reg + iv * gv;
    c_reg = c;
    float h = ov * tanhf_fast(c);

    out[(size_t)erow * (T_STEPS * HID) + (size_t)t * HID + j * 16 + ecol] = h;
    hbuf[(size_t)((t + 1) & 1) * (BATCH * HID) + (size_t)erow * HID + j * 16 + ecol] = f2bf(h);

    __threadfence();   // release: make h visible agent-wide
    __syncthreads();
    if (tid == 0) __hip_atomic_fetch_add(cnt, 1u, __ATOMIC_RELEASE, __HIP_MEMORY_SCOPE_AGENT);

    for (int r = 0; r < 4; r++) xgv[r] = xgn[r];
  }
}

// ---------------- host ----------------
extern "C" void kernel_launch(void* const* d_in, const int* in_sizes, int n_in,
                              void* d_out, int out_size, void* d_ws, size_t ws_size,
                              hipStream_t stream) {
  (void)in_sizes; (void)n_in; (void)out_size;
  if (ws_size < WS_NEED) return;  // workspace too small: bail (visible as failed validation)

  const float* x   = (const float*)d_in[0];
  const float* wih = (const float*)d_in[1];
  const float* whh = (const float*)d_in[2];
  const float* bih = (const float*)d_in[3];
  const float* bhh = (const float*)d_in[4];
  float* out = (float*)d_out;
  char* ws = (char*)d_ws;

  ushort_t* xg_b   = (ushort_t*)(ws + XG_OFF);
  ushort_t* xT_b   = (ushort_t*)(ws + XT_OFF);
  ushort_t* wih_b  = (ushort_t*)(ws + WIH_OFF);
  ushort_t* whh_b  = (ushort_t*)(ws + WHH_OFF);
  ushort_t* hbuf   = (ushort_t*)(ws + HBUF_OFF);
  uint_t*   cnt    = (uint_t*)(ws + CNT_OFF);

  // zero h0 double-buffer + barrier counter (ws is poisoned 0xAA each call)
  hipMemsetAsync(ws + HBUF_OFF, 0, 32768 + 256, stream);

  conv_x_k<<<24576, 256, 0, stream>>>((const float4*)x, xT_b);
  conv_w_k<<<1536, 256, 0, stream>>>((const float4*)wih, wih_b, 393216u);
  conv_w_k<<<1024, 256, 0, stream>>>((const float4*)whh, whh_b, 262144u);
  gemm_xg<<<dim3(16, 256), 256, 0, stream>>>(xT_b, wih_b, bih, bhh, xg_b);
  lstm_rec<<<NBLK, 256, 0, stream>>>(xg_b, whh_b, hbuf, cnt, out);
}

// Round 2
// 11043.579 us; speedup vs baseline: 1.7120x; 1.7120x over previous
//
#include <hip/hip_runtime.h>
#include <hip/hip_bf16.h>
#include <stdint.h>

typedef unsigned short ushort_t;
typedef unsigned int uint_t;
typedef unsigned long long ull_t;
typedef __attribute__((ext_vector_type(8))) short short8;
typedef __attribute__((ext_vector_type(4))) float floatx4;

#define T_STEPS 2048
#define BATCH 16
#define IN_F 768
#define HID 512
#define G4 2048   // 4*HID
#define NBLK 32   // phase-2 blocks

// ---------------- workspace layout (bytes) ----------------
// xg   bf16 [T][16][2048]            : 134217728
// xT   bf16 [32768][768]             :  50331648
// wih  bf16 [2048][768]              :   3145728
// whh  bf16 [2048][512]              :   2097152
// hbuf bf16 [2][16][512]             :     32768
// flags u32 [32][16]  (one/64B line) :      2048
static const size_t XG_OFF   = 0;
static const size_t XT_OFF   = 134217728ull;
static const size_t WIH_OFF  = XT_OFF + 50331648ull;
static const size_t WHH_OFF  = WIH_OFF + 3145728ull;
static const size_t HBUF_OFF = WHH_OFF + 2097152ull;
static const size_t FLG_OFF  = HBUF_OFF + 32768ull;
static const size_t WS_NEED  = FLG_OFF + 2048ull;

// ---------------- helpers ----------------
__device__ inline ushort_t f2bf(float f) {
  uint_t u = __float_as_uint(f);
  u = (u + 0x7FFFu + ((u >> 16) & 1u)) >> 16;
  return (ushort_t)u;
}
__device__ inline float bf2f(ushort_t h) {
  return __uint_as_float(((uint_t)h) << 16);
}
__device__ inline floatx4 mfma16(short8 a, short8 b, floatx4 c) {
  return __builtin_amdgcn_mfma_f32_16x16x32_bf16(a, b, c, 0, 0, 0);
}
__device__ inline void ld_g2l16(const void* g, void* l) {
  __builtin_amdgcn_global_load_lds(
      (const __attribute__((address_space(1))) unsigned int*)g,
      (__attribute__((address_space(3))) unsigned int*)l, 16, 0, 0);
}
__device__ inline float sigf(float x) {
  float e = __expf(-x);
  return __fdividef(1.0f, 1.0f + e);
}
__device__ inline float tanhf_fast(float x) {
  x = fminf(fmaxf(x, -15.0f), 15.0f);
  float e = __expf(2.0f * x);
  return __fdividef(e - 1.0f, e + 1.0f);
}
// coherent (agent-scope, L1/L2-bypassing) accesses — NO cache-wide flushes
__device__ inline uint_t cload32(const uint_t* p) {
  return __hip_atomic_load(p, __ATOMIC_RELAXED, __HIP_MEMORY_SCOPE_AGENT);
}
__device__ inline ull_t cload64(const ull_t* p) {
  return __hip_atomic_load(p, __ATOMIC_RELAXED, __HIP_MEMORY_SCOPE_AGENT);
}
__device__ inline void cstore32(uint_t* p, uint_t v) {
  __hip_atomic_store(p, v, __ATOMIC_RELAXED, __HIP_MEMORY_SCOPE_AGENT);
}

// ---------------- phase 0: converts ----------------
__global__ __launch_bounds__(256) void conv_x_k(const float4* __restrict__ x,
                                                ushort_t* __restrict__ xT) {
  uint_t idx = blockIdx.x * 256u + threadIdx.x;  // < 6291456 exactly
  float4 v = x[idx];
  uint_t e = idx * 4u;
  uint_t k = e % 768u;
  uint_t rin = e / 768u;          // b*2048 + t
  uint_t b = rin >> 11, t = rin & 2047u;
  size_t o = (size_t)(t * 16u + b) * 768u + k;
  ushort4 r;
  r.x = f2bf(v.x); r.y = f2bf(v.y); r.z = f2bf(v.z); r.w = f2bf(v.w);
  *(ushort4*)(xT + o) = r;
}

__global__ __launch_bounds__(256) void conv_w_k(const float4* __restrict__ src,
                                                ushort_t* __restrict__ dst, uint_t n4) {
  uint_t idx = blockIdx.x * 256u + threadIdx.x;
  if (idx >= n4) return;
  float4 v = src[idx];
  ushort4 r;
  r.x = f2bf(v.x); r.y = f2bf(v.y); r.z = f2bf(v.z); r.w = f2bf(v.w);
  *(ushort4*)(dst + (size_t)idx * 4u) = r;
}

// ---------------- phase 1: xg = xT @ wih^T + bias, bf16 out ----------------
__global__ __launch_bounds__(256) void gemm_xg(const ushort_t* __restrict__ A,
                                               const ushort_t* __restrict__ Bw,
                                               const float* __restrict__ bih,
                                               const float* __restrict__ bhh,
                                               ushort_t* __restrict__ xg) {
  __shared__ __align__(16) ushort_t Asm[128 * 64];
  __shared__ __align__(16) ushort_t Bsm[128 * 64];
  const int tid = threadIdx.x;
  const int w = tid >> 6, l = tid & 63;
  const int m_ = l & 15, q = l >> 4;
  const int lr = l >> 3, lc = l & 7;
  const int nt = blockIdx.x, mt = blockIdx.y;
  const int wr = (w >> 1) * 64, wc = (w & 1) * 64;

  floatx4 acc[4][4];
  for (int i = 0; i < 4; i++)
    for (int j = 0; j < 4; j++) acc[i][j] = (floatx4){0.f, 0.f, 0.f, 0.f};

  for (int it = 0; it < 12; ++it) {
    const int K0 = it * 64;
    for (int p = 0; p < 4; p++) {
      int row = w * 32 + p * 8 + lr;
      int c = lc ^ lr;
      ld_g2l16(A + (size_t)(mt * 128 + row) * 768 + K0 + c * 8,
               Asm + (size_t)(w * 32 + p * 8) * 64);
      ld_g2l16(Bw + (size_t)(nt * 128 + row) * 768 + K0 + c * 8,
               Bsm + (size_t)(w * 32 + p * 8) * 64);
    }
    __syncthreads();
    short8 af[2][4], bfr[2][4];
    for (int kk = 0; kk < 2; kk++) {
      int chunk = kk * 4 + q;
      for (int rt = 0; rt < 4; rt++) {
        int row = wr + rt * 16 + m_;
        af[kk][rt] = *(const short8*)(Asm + (size_t)row * 64 + (size_t)(chunk ^ (row & 7)) * 8);
        int col = wc + rt * 16 + m_;
        bfr[kk][rt] = *(const short8*)(Bsm + (size_t)col * 64 + (size_t)(chunk ^ (col & 7)) * 8);
      }
    }
    for (int kk = 0; kk < 2; kk++)
      for (int rt = 0; rt < 4; rt++)
        for (int ct = 0; ct < 4; ct++)
          acc[rt][ct] = mfma16(af[kk][rt], bfr[kk][ct], acc[rt][ct]);
    __syncthreads();
  }
  for (int ct = 0; ct < 4; ct++) {
    int gcol = nt * 128 + wc + ct * 16 + m_;
    float bias = bih[gcol] + bhh[gcol];
    for (int rt = 0; rt < 4; rt++) {
      int growb = mt * 128 + wr + rt * 16 + q * 4;
      for (int r = 0; r < 4; r++)
        xg[(size_t)(growb + r) * G4 + gcol] = f2bf(acc[rt][ct][r] + bias);
    }
  }
}

// ---------------- phase 2: persistent recurrent kernel ----------------
// 32 blocks x 256 threads. Block j owns h cols [16j,16j+16). Wave w = gate group w.
// h exchange via coherent (sc0 sc1) loads/stores through L3 — no cache flushes.
__global__ __launch_bounds__(256) void lstm_rec(const ushort_t* __restrict__ xg,
                                                const ushort_t* __restrict__ whh,
                                                uint_t* hbuf32, uint_t* flags,
                                                float* __restrict__ out) {
  const int tid = threadIdx.x;
  const int w = tid >> 6, l = tid & 63;
  const int m_ = l & 15, q = l >> 4;
  const int j = blockIdx.x;
  const int gcolb = w * HID + j * 16;   // gate column base for this wave

  // pin w_hh slice in registers: B[k][n], lane n=m_, k=kk*32+q*8+jj
  short8 bfrag[16];
  {
    const ushort_t* wrow = whh + (size_t)(gcolb + m_) * HID + q * 8;
    for (int kk = 0; kk < 16; kk++) bfrag[kk] = *(const short8*)(wrow + kk * 32);
  }

  const int erow = tid >> 4, ecol = tid & 15;  // epilogue ownership (batch row, h col)
  const int fl = l & 31;                       // flag index this lane polls
  float c_reg = 0.f;
  __shared__ float gsm[4][16][17];

  // xg frags for t=0 (C-layout init: reg r -> batch row q*4+r, col m_)
  ushort_t xgv[4];
  {
    const ushort_t* p = xg + (size_t)(q * 4) * G4 + gcolb + m_;
    for (int r = 0; r < 4; r++) xgv[r] = p[(size_t)r * G4];
  }

  for (int t = 0; t < T_STEPS; t++) {
    // prefetch next step's xg (plain cached loads, independent of h)
    ushort_t xgn[4];
    {
      int tt = (t + 1 < T_STEPS) ? (t + 1) : t;
      const ushort_t* p = xg + ((size_t)tt * 16 + q * 4) * G4 + gcolb + m_;
      for (int r = 0; r < 4; r++) xgn[r] = p[(size_t)r * G4];
    }
    // wait until every block has published h(t) (flag[j] >= t). Each wave polls
    // independently: lanes 0..31 poll flag[lane] (lanes 32..63 duplicate).
    if (t > 0) {
      for (;;) {
        uint_t v = cload32(flags + fl * 16);
        if (__all((int)(v >= (uint_t)t))) break;
      }
    }
    // A frags from h double buffer via coherent 8B loads:
    // A[m][k], lane m=m_, k = kk*32 + q*8 + jj  -> u32 index kk*16 + q*4
    const uint_t* hb = hbuf32 + (size_t)(t & 1) * (BATCH * HID / 2) + (size_t)m_ * 256 + q * 4;
    short8 af[16];
    for (int kk = 0; kk < 16; kk++) {
      union { ull_t u[2]; short8 s; } cv;
      cv.u[0] = cload64((const ull_t*)(hb + kk * 16));
      cv.u[1] = cload64((const ull_t*)(hb + kk * 16 + 2));
      af[kk] = cv.s;
    }

    floatx4 acc0 = (floatx4){bf2f(xgv[0]), bf2f(xgv[1]), bf2f(xgv[2]), bf2f(xgv[3])};
    floatx4 acc1 = (floatx4){0.f, 0.f, 0.f, 0.f};
    for (int kk = 0; kk < 16; kk += 2) {
      acc0 = mfma16(af[kk], bfrag[kk], acc0);
      acc1 = mfma16(af[kk + 1], bfrag[kk + 1], acc1);
    }
    floatx4 acc = acc0 + acc1;

    for (int r = 0; r < 4; r++) gsm[w][q * 4 + r][m_] = acc[r];
    __syncthreads();

    float iv = sigf(gsm[0][erow][ecol]);
    float fv = sigf(gsm[1][erow][ecol]);
    float gv = tanhf_fast(gsm[2][erow][ecol]);
    float ov = sigf(gsm[3][erow][ecol]);
    float c = fv * c_reg + iv * gv;
    c_reg = c;
    float h = ov * tanhf_fast(c);

    out[(size_t)erow * (T_STEPS * HID) + (size_t)t * HID + j * 16 + ecol] = h;

    // publish h(t+1): pack bf16 pair via shuffle, coherent u32 store (even lanes)
    uint_t hu = (uint_t)f2bf(h);
    uint_t hn = (uint_t)__shfl_xor((int)hu, 1);
    if ((ecol & 1) == 0) {
      uint_t packed = hu | (hn << 16);
      cstore32(hbuf32 + (size_t)((t + 1) & 1) * (BATCH * HID / 2) + (size_t)erow * 256 +
                   (uint_t)(j * 16 + ecol) / 2,
               packed);
    }
    // __syncthreads drains vmcnt(0) per wave -> coherent stores have reached L3
    __syncthreads();
    if (tid == 0) cstore32(flags + j * 16, (uint_t)(t + 1));

    for (int r = 0; r < 4; r++) xgv[r] = xgn[r];
  }
}

// ---------------- host ----------------
extern "C" void kernel_launch(void* const* d_in, const int* in_sizes, int n_in,
                              void* d_out, int out_size, void* d_ws, size_t ws_size,
                              hipStream_t stream) {
  (void)in_sizes; (void)n_in; (void)out_size;
  if (ws_size < WS_NEED) return;

  const float* x   = (const float*)d_in[0];
  const float* wih = (const float*)d_in[1];
  const float* whh = (const float*)d_in[2];
  const float* bih = (const float*)d_in[3];
  const float* bhh = (const float*)d_in[4];
  float* out = (float*)d_out;
  char* ws = (char*)d_ws;

  ushort_t* xg_b   = (ushort_t*)(ws + XG_OFF);
  ushort_t* xT_b   = (ushort_t*)(ws + XT_OFF);
  ushort_t* wih_b  = (ushort_t*)(ws + WIH_OFF);
  ushort_t* whh_b  = (ushort_t*)(ws + WHH_OFF);
  uint_t*   hbuf32 = (uint_t*)(ws + HBUF_OFF);
  uint_t*   flags  = (uint_t*)(ws + FLG_OFF);

  // zero h0 double-buffer + flags (ws is poisoned 0xAA each call)
  hipMemsetAsync(ws + HBUF_OFF, 0, 32768 + 2048, stream);

  conv_x_k<<<24576, 256, 0, stream>>>((const float4*)x, xT_b);
  conv_w_k<<<1536, 256, 0, stream>>>((const float4*)wih, wih_b, 393216u);
  conv_w_k<<<1024, 256, 0, stream>>>((const float4*)whh, whh_b, 262144u);
  gemm_xg<<<dim3(16, 256), 256, 0, stream>>>(xT_b, wih_b, bih, bhh, xg_b);
  lstm_rec<<<NBLK, 256, 0, stream>>>(xg_b, whh_b, hbuf32, flags, out);
}

// Round 3
// 5707.542 us; speedup vs baseline: 3.3126x; 1.9349x over previous
//
#include <hip/hip_runtime.h>
#include <hip/hip_bf16.h>
#include <stdint.h>

typedef unsigned short ushort_t;
typedef unsigned int uint_t;
typedef unsigned long long ull_t;
typedef __attribute__((ext_vector_type(8))) short short8;
typedef __attribute__((ext_vector_type(4))) float floatx4;

#define T_STEPS 2048
#define BATCH 16
#define IN_F 768
#define HID 512
#define G4 2048   // 4*HID
#define NBLK 32   // phase-2 blocks

// ---------------- workspace layout (bytes) ----------------
static const size_t XG_OFF   = 0;                       // xg bf16 [T][16][2048]
static const size_t XT_OFF   = 134217728ull;            // xT bf16 [32768][768]
static const size_t WIH_OFF  = XT_OFF + 50331648ull;    // wih bf16 [2048][768]
static const size_t WHH_OFF  = WIH_OFF + 3145728ull;    // whh bf16 [2048][512]
static const size_t HBUF_OFF = WHH_OFF + 2097152ull;    // hbuf bf16 [2][16][512]
static const size_t FLG_OFF  = HBUF_OFF + 32768ull;     // flags u32 [32][16]
static const size_t WS_NEED  = FLG_OFF + 2048ull;

// ---------------- helpers ----------------
__device__ inline ushort_t f2bf(float f) {
  uint_t u = __float_as_uint(f);
  u = (u + 0x7FFFu + ((u >> 16) & 1u)) >> 16;
  return (ushort_t)u;
}
__device__ inline float bf2f(ushort_t h) {
  return __uint_as_float(((uint_t)h) << 16);
}
__device__ inline floatx4 mfma16(short8 a, short8 b, floatx4 c) {
  return __builtin_amdgcn_mfma_f32_16x16x32_bf16(a, b, c, 0, 0, 0);
}
__device__ inline void ld_g2l16(const void* g, void* l) {
  __builtin_amdgcn_global_load_lds(
      (const __attribute__((address_space(1))) unsigned int*)g,
      (__attribute__((address_space(3))) unsigned int*)l, 16, 0, 0);
}
__device__ inline float sigf(float x) {
  float e = __expf(-x);
  return __fdividef(1.0f, 1.0f + e);
}
__device__ inline float tanhf_fast(float x) {
  x = fminf(fmaxf(x, -15.0f), 15.0f);
  float e = __expf(2.0f * x);
  return __fdividef(e - 1.0f, e + 1.0f);
}
// coherent (agent-scope, L1/L2-bypassing) accesses — no cache-wide flushes
__device__ inline uint_t cload32(const uint_t* p) {
  return __hip_atomic_load(p, __ATOMIC_RELAXED, __HIP_MEMORY_SCOPE_AGENT);
}
__device__ inline ull_t cload64(const ull_t* p) {
  return __hip_atomic_load(p, __ATOMIC_RELAXED, __HIP_MEMORY_SCOPE_AGENT);
}
__device__ inline void cstore32(uint_t* p, uint_t v) {
  __hip_atomic_store(p, v, __ATOMIC_RELAXED, __HIP_MEMORY_SCOPE_AGENT);
}

// ---------------- phase 0: converts ----------------
__global__ __launch_bounds__(256) void conv_x_k(const float4* __restrict__ x,
                                                ushort_t* __restrict__ xT) {
  uint_t idx = blockIdx.x * 256u + threadIdx.x;  // < 6291456 exactly
  float4 v = x[idx];
  uint_t e = idx * 4u;
  uint_t k = e % 768u;
  uint_t rin = e / 768u;          // b*2048 + t
  uint_t b = rin >> 11, t = rin & 2047u;
  size_t o = (size_t)(t * 16u + b) * 768u + k;
  ushort4 r;
  r.x = f2bf(v.x); r.y = f2bf(v.y); r.z = f2bf(v.z); r.w = f2bf(v.w);
  *(ushort4*)(xT + o) = r;
}

__global__ __launch_bounds__(256) void conv_w_k(const float4* __restrict__ src,
                                                ushort_t* __restrict__ dst, uint_t n4) {
  uint_t idx = blockIdx.x * 256u + threadIdx.x;
  if (idx >= n4) return;
  float4 v = src[idx];
  ushort4 r;
  r.x = f2bf(v.x); r.y = f2bf(v.y); r.z = f2bf(v.z); r.w = f2bf(v.w);
  *(ushort4*)(dst + (size_t)idx * 4u) = r;
}

// ---------------- phase 1: xg = xT @ wih^T + bias, bf16 out ----------------
__global__ __launch_bounds__(256) void gemm_xg(const ushort_t* __restrict__ A,
                                               const ushort_t* __restrict__ Bw,
                                               const float* __restrict__ bih,
                                               const float* __restrict__ bhh,
                                               ushort_t* __restrict__ xg) {
  __shared__ __align__(16) ushort_t Asm[128 * 64];
  __shared__ __align__(16) ushort_t Bsm[128 * 64];
  const int tid = threadIdx.x;
  const int w = tid >> 6, l = tid & 63;
  const int m_ = l & 15, q = l >> 4;
  const int lr = l >> 3, lc = l & 7;
  const int nt = blockIdx.x, mt = blockIdx.y;
  const int wr = (w >> 1) * 64, wc = (w & 1) * 64;

  floatx4 acc[4][4];
  for (int i = 0; i < 4; i++)
    for (int j = 0; j < 4; j++) acc[i][j] = (floatx4){0.f, 0.f, 0.f, 0.f};

  for (int it = 0; it < 12; ++it) {
    const int K0 = it * 64;
    for (int p = 0; p < 4; p++) {
      int row = w * 32 + p * 8 + lr;
      int c = lc ^ lr;
      ld_g2l16(A + (size_t)(mt * 128 + row) * 768 + K0 + c * 8,
               Asm + (size_t)(w * 32 + p * 8) * 64);
      ld_g2l16(Bw + (size_t)(nt * 128 + row) * 768 + K0 + c * 8,
               Bsm + (size_t)(w * 32 + p * 8) * 64);
    }
    __syncthreads();
    short8 af[2][4], bfr[2][4];
    for (int kk = 0; kk < 2; kk++) {
      int chunk = kk * 4 + q;
      for (int rt = 0; rt < 4; rt++) {
        int row = wr + rt * 16 + m_;
        af[kk][rt] = *(const short8*)(Asm + (size_t)row * 64 + (size_t)(chunk ^ (row & 7)) * 8);
        int col = wc + rt * 16 + m_;
        bfr[kk][rt] = *(const short8*)(Bsm + (size_t)col * 64 + (size_t)(chunk ^ (col & 7)) * 8);
      }
    }
    for (int kk = 0; kk < 2; kk++)
      for (int rt = 0; rt < 4; rt++)
        for (int ct = 0; ct < 4; ct++)
          acc[rt][ct] = mfma16(af[kk][rt], bfr[kk][ct], acc[rt][ct]);
    __syncthreads();
  }
  for (int ct = 0; ct < 4; ct++) {
    int gcol = nt * 128 + wc + ct * 16 + m_;
    float bias = bih[gcol] + bhh[gcol];
    for (int rt = 0; rt < 4; rt++) {
      int growb = mt * 128 + wr + rt * 16 + q * 4;
      for (int r = 0; r < 4; r++)
        xg[(size_t)(growb + r) * G4 + gcol] = f2bf(acc[rt][ct][r] + bias);
    }
  }
}

// ---------------- phase 2: persistent recurrent kernel ----------------
// 32 blocks x 256 threads. Block j owns h cols [16j,16j+16). Wave w = gate group w.
// Per step: wave0 polls flags -> block stages h (16KB) from L3 into LDS with
// coalesced coherent loads (one latency) -> MFMA from LDS frags -> gates ->
// coherent h store -> flag. XOR swizzle (chunk ^ (row&7)) keeps LDS at
// structural-minimum banking for both b128 writes and reads.
__global__ __launch_bounds__(256, 1) void lstm_rec(const ushort_t* __restrict__ xg,
                                                   const ushort_t* __restrict__ whh,
                                                   uint_t* hbuf32, uint_t* flags,
                                                   float* __restrict__ out) {
  const int tid = threadIdx.x;
  const int w = tid >> 6, l = tid & 63;
  const int m_ = l & 15, q = l >> 4;
  const int j = blockIdx.x;
  const int gcolb = w * HID + j * 16;   // gate column base for this wave

  // pin w_hh slice in registers: B[k][n], lane n=m_, k=kk*32+q*8+jj
  short8 bfrag[16];
  {
    const ushort_t* wrow = whh + (size_t)(gcolb + m_) * HID + q * 8;
    for (int kk = 0; kk < 16; kk++) bfrag[kk] = *(const short8*)(wrow + kk * 32);
  }

  const int erow = tid >> 4, ecol = tid & 15;  // epilogue ownership (batch row, h col)
  float c_reg = 0.f;
  __shared__ float gsm[4][16][17];
  __shared__ __align__(16) ushort_t hsm[BATCH * HID];   // 16 KB, swizzled

  // staging geometry: thread covers bytes [tid*64, tid*64+64) of h buffer
  const int srow = tid >> 4;            // h row this thread stages
  const int scb  = (tid & 15) * 4;      // first 16B-chunk within row

  // xg frags for t=0 (C-layout init: reg r -> batch row q*4+r, col m_)
  ushort_t xgv[4];
  {
    const ushort_t* p = xg + (size_t)(q * 4) * G4 + gcolb + m_;
    for (int r = 0; r < 4; r++) xgv[r] = p[(size_t)r * G4];
  }

  for (int t = 0; t < T_STEPS; t++) {
    // prefetch next step's xg (plain cached loads, independent of h)
    ushort_t xgn[4];
    {
      int tt = (t + 1 < T_STEPS) ? (t + 1) : t;
      const ushort_t* p = xg + ((size_t)tt * 16 + q * 4) * G4 + gcolb + m_;
      for (int r = 0; r < 4; r++) xgn[r] = p[(size_t)r * G4];
    }
    // wave 0 polls until every block has published h(t)
    if (t > 0) {
      if (w == 0) {
        const int fl = l & 31;
        for (;;) {
          uint_t v = cload32(flags + fl * 16);
          if (__all((int)(v >= (uint_t)t))) break;
        }
      }
      __syncthreads();
    }
    // cooperative stage: hbuf[t&1] (16KB) -> hsm, coherent 8B loads, all independent
    {
      const ull_t* gp = (const ull_t*)(hbuf32 + (size_t)(t & 1) * (BATCH * HID / 2));
      ull_t v[8];
      for (int k = 0; k < 8; k++) v[k] = cload64(gp + (size_t)tid * 8 + k);
      for (int i = 0; i < 4; i++) {
        int c = scb + i;
        int p = c ^ (srow & 7);
        union { ull_t u[2]; short8 s; } cv;
        cv.u[0] = v[2 * i]; cv.u[1] = v[2 * i + 1];
        *(short8*)(hsm + (size_t)srow * HID + p * 8) = cv.s;
      }
    }
    __syncthreads();

    // A frags from LDS: lane m=m_, logical chunk (q + 4*kk) of row m_
    short8 af[16];
    for (int kk = 0; kk < 16; kk++) {
      int p = (q + 4 * kk) ^ (m_ & 7);
      af[kk] = *(const short8*)(hsm + (size_t)m_ * HID + p * 8);
    }

    floatx4 acc0 = (floatx4){bf2f(xgv[0]), bf2f(xgv[1]), bf2f(xgv[2]), bf2f(xgv[3])};
    floatx4 acc1 = (floatx4){0.f, 0.f, 0.f, 0.f};
    for (int kk = 0; kk < 16; kk += 2) {
      acc0 = mfma16(af[kk], bfrag[kk], acc0);
      acc1 = mfma16(af[kk + 1], bfrag[kk + 1], acc1);
    }
    floatx4 acc = acc0 + acc1;

    for (int r = 0; r < 4; r++) gsm[w][q * 4 + r][m_] = acc[r];
    __syncthreads();

    float iv = sigf(gsm[0][erow][ecol]);
    float fv = sigf(gsm[1][erow][ecol]);
    float gv = tanhf_fast(gsm[2][erow][ecol]);
    float ov = sigf(gsm[3][erow][ecol]);
    float c = fv * c_reg + iv * gv;
    c_reg = c;
    float h = ov * tanhf_fast(c);

    // publish h(t+1): pack bf16 pair via shuffle, coherent u32 store (even lanes)
    uint_t hu = (uint_t)f2bf(h);
    uint_t hn = (uint_t)__shfl_xor((int)hu, 1);
    if ((ecol & 1) == 0) {
      uint_t packed = hu | (hn << 16);
      cstore32(hbuf32 + (size_t)((t + 1) & 1) * (BATCH * HID / 2) + (size_t)erow * 256 +
                   (uint_t)(j * 16 + ecol) / 2,
               packed);
    }
    // __syncthreads drains vmcnt(0) per wave -> coherent stores have reached L3
    __syncthreads();
    if (tid == 0) cstore32(flags + j * 16, (uint_t)(t + 1));

    // off the critical path: plain out store + xg rotate
    out[(size_t)erow * (T_STEPS * HID) + (size_t)t * HID + j * 16 + ecol] = h;
    for (int r = 0; r < 4; r++) xgv[r] = xgn[r];
  }
}

// ---------------- host ----------------
extern "C" void kernel_launch(void* const* d_in, const int* in_sizes, int n_in,
                              void* d_out, int out_size, void* d_ws, size_t ws_size,
                              hipStream_t stream) {
  (void)in_sizes; (void)n_in; (void)out_size;
  if (ws_size < WS_NEED) return;

  const float* x   = (const float*)d_in[0];
  const float* wih = (const float*)d_in[1];
  const float* whh = (const float*)d_in[2];
  const float* bih = (const float*)d_in[3];
  const float* bhh = (const float*)d_in[4];
  float* out = (float*)d_out;
  char* ws = (char*)d_ws;

  ushort_t* xg_b   = (ushort_t*)(ws + XG_OFF);
  ushort_t* xT_b   = (ushort_t*)(ws + XT_OFF);
  ushort_t* wih_b  = (ushort_t*)(ws + WIH_OFF);
  ushort_t* whh_b  = (ushort_t*)(ws + WHH_OFF);
  uint_t*   hbuf32 = (uint_t*)(ws + HBUF_OFF);
  uint_t*   flags  = (uint_t*)(ws + FLG_OFF);

  // zero h0 double-buffer + flags (ws is poisoned 0xAA each call)
  hipMemsetAsync(ws + HBUF_OFF, 0, 32768 + 2048, stream);

  conv_x_k<<<24576, 256, 0, stream>>>((const float4*)x, xT_b);
  conv_w_k<<<1536, 256, 0, stream>>>((const float4*)wih, wih_b, 393216u);
  conv_w_k<<<1024, 256, 0, stream>>>((const float4*)whh, whh_b, 262144u);
  gemm_xg<<<dim3(16, 256), 256, 0, stream>>>(xT_b, wih_b, bih, bhh, xg_b);
  lstm_rec<<<NBLK, 256, 0, stream>>>(xg_b, whh_b, hbuf32, flags, out);
}

// Round 4
// 4836.861 us; speedup vs baseline: 3.9089x; 1.1800x over previous
//
#include <hip/hip_runtime.h>
#include <hip/hip_bf16.h>
#include <stdint.h>

typedef unsigned short ushort_t;
typedef unsigned int uint_t;
typedef unsigned long long ull_t;
typedef __attribute__((ext_vector_type(8))) short short8;
typedef __attribute__((ext_vector_type(4))) float floatx4;

#define T_STEPS 2048
#define BATCH 16
#define IN_F 768
#define HID 512
#define G4 2048   // 4*HID
#define NBLK 32   // phase-2 blocks

// ---------------- workspace layout (bytes) ----------------
static const size_t XG_OFF   = 0;                       // xg bf16 [T][16][2048]
static const size_t XT_OFF   = 134217728ull;            // xT bf16 [32768][768]
static const size_t WIH_OFF  = XT_OFF + 50331648ull;    // wih bf16 [2048][768]
static const size_t WHH_OFF  = WIH_OFF + 3145728ull;    // whh bf16 [2048][512]
static const size_t HBUF_OFF = WHH_OFF + 2097152ull;    // hbuf u32 [2][16][512] tagged
static const size_t WS_NEED  = HBUF_OFF + 65536ull;

// ---------------- helpers ----------------
__device__ inline ushort_t f2bf(float f) {
  uint_t u = __float_as_uint(f);
  u = (u + 0x7FFFu + ((u >> 16) & 1u)) >> 16;
  return (ushort_t)u;
}
__device__ inline float bf2f(ushort_t h) {
  return __uint_as_float(((uint_t)h) << 16);
}
__device__ inline floatx4 mfma16(short8 a, short8 b, floatx4 c) {
  return __builtin_amdgcn_mfma_f32_16x16x32_bf16(a, b, c, 0, 0, 0);
}
__device__ inline void ld_g2l16(const void* g, void* l) {
  __builtin_amdgcn_global_load_lds(
      (const __attribute__((address_space(1))) unsigned int*)g,
      (__attribute__((address_space(3))) unsigned int*)l, 16, 0, 0);
}
__device__ inline float sigf(float x) {
  float e = __expf(-x);
  return __fdividef(1.0f, 1.0f + e);
}
__device__ inline float tanhf_fast(float x) {
  x = fminf(fmaxf(x, -15.0f), 15.0f);
  float e = __expf(2.0f * x);
  return __fdividef(e - 1.0f, e + 1.0f);
}
// coherent (agent-scope, L2-bypassing) accesses — no cache-wide flushes
__device__ inline ull_t cload64(const ull_t* p) {
  return __hip_atomic_load(p, __ATOMIC_RELAXED, __HIP_MEMORY_SCOPE_AGENT);
}
__device__ inline void cstore32(uint_t* p, uint_t v) {
  __hip_atomic_store(p, v, __ATOMIC_RELAXED, __HIP_MEMORY_SCOPE_AGENT);
}

// ---------------- phase 0: converts ----------------
__global__ __launch_bounds__(256) void conv_x_k(const float4* __restrict__ x,
                                                ushort_t* __restrict__ xT) {
  uint_t idx = blockIdx.x * 256u + threadIdx.x;  // < 6291456 exactly
  float4 v = x[idx];
  uint_t e = idx * 4u;
  uint_t k = e % 768u;
  uint_t rin = e / 768u;          // b*2048 + t
  uint_t b = rin >> 11, t = rin & 2047u;
  size_t o = (size_t)(t * 16u + b) * 768u + k;
  ushort4 r;
  r.x = f2bf(v.x); r.y = f2bf(v.y); r.z = f2bf(v.z); r.w = f2bf(v.w);
  *(ushort4*)(xT + o) = r;
}

__global__ __launch_bounds__(256) void conv_w_k(const float4* __restrict__ src,
                                                ushort_t* __restrict__ dst, uint_t n4) {
  uint_t idx = blockIdx.x * 256u + threadIdx.x;
  if (idx >= n4) return;
  float4 v = src[idx];
  ushort4 r;
  r.x = f2bf(v.x); r.y = f2bf(v.y); r.z = f2bf(v.z); r.w = f2bf(v.w);
  *(ushort4*)(dst + (size_t)idx * 4u) = r;
}

// ---------------- phase 1: xg = xT @ wih^T + bias, bf16 out ----------------
__global__ __launch_bounds__(256) void gemm_xg(const ushort_t* __restrict__ A,
                                               const ushort_t* __restrict__ Bw,
                                               const float* __restrict__ bih,
                                               const float* __restrict__ bhh,
                                               ushort_t* __restrict__ xg) {
  __shared__ __align__(16) ushort_t Asm[128 * 64];
  __shared__ __align__(16) ushort_t Bsm[128 * 64];
  const int tid = threadIdx.x;
  const int w = tid >> 6, l = tid & 63;
  const int m_ = l & 15, q = l >> 4;
  const int lr = l >> 3, lc = l & 7;
  const int nt = blockIdx.x, mt = blockIdx.y;
  const int wr = (w >> 1) * 64, wc = (w & 1) * 64;

  floatx4 acc[4][4];
  for (int i = 0; i < 4; i++)
    for (int j = 0; j < 4; j++) acc[i][j] = (floatx4){0.f, 0.f, 0.f, 0.f};

  for (int it = 0; it < 12; ++it) {
    const int K0 = it * 64;
    for (int p = 0; p < 4; p++) {
      int row = w * 32 + p * 8 + lr;
      int c = lc ^ lr;
      ld_g2l16(A + (size_t)(mt * 128 + row) * 768 + K0 + c * 8,
               Asm + (size_t)(w * 32 + p * 8) * 64);
      ld_g2l16(Bw + (size_t)(nt * 128 + row) * 768 + K0 + c * 8,
               Bsm + (size_t)(w * 32 + p * 8) * 64);
    }
    __syncthreads();
    short8 af[2][4], bfr[2][4];
    for (int kk = 0; kk < 2; kk++) {
      int chunk = kk * 4 + q;
      for (int rt = 0; rt < 4; rt++) {
        int row = wr + rt * 16 + m_;
        af[kk][rt] = *(const short8*)(Asm + (size_t)row * 64 + (size_t)(chunk ^ (row & 7)) * 8);
        int col = wc + rt * 16 + m_;
        bfr[kk][rt] = *(const short8*)(Bsm + (size_t)col * 64 + (size_t)(chunk ^ (col & 7)) * 8);
      }
    }
    for (int kk = 0; kk < 2; kk++)
      for (int rt = 0; rt < 4; rt++)
        for (int ct = 0; ct < 4; ct++)
          acc[rt][ct] = mfma16(af[kk][rt], bfr[kk][ct], acc[rt][ct]);
    __syncthreads();
  }
  for (int ct = 0; ct < 4; ct++) {
    int gcol = nt * 128 + wc + ct * 16 + m_;
    float bias = bih[gcol] + bhh[gcol];
    for (int rt = 0; rt < 4; rt++) {
      int growb = mt * 128 + wr + rt * 16 + q * 4;
      for (int r = 0; r < 4; r++)
        xg[(size_t)(growb + r) * G4 + gcol] = f2bf(acc[rt][ct][r] + bias);
    }
  }
}

// ---------------- phase 2: persistent recurrent kernel ----------------
// 32 blocks x 256 threads. Block j owns h cols [16j,16j+16).
// K-split: wave w reduces K in [128w,128w+128) for ALL 4 gates; partials summed
// via double-buffered gsm (one __syncthreads per step).
// h exchange: tagged u32 (tag<<16 | bf16). Producers store-and-go (no drain, no
// flags). Consumers poll their own slice; the passing poll IS the data load.
// Safety: writing tag t+2 into a buffer requires having observed all blocks'
// t+1 tags, which requires every block passed its step-t poll (double buffer).
__global__ __launch_bounds__(256, 1) void lstm_rec(const ushort_t* __restrict__ xg,
                                                   const ushort_t* __restrict__ whh,
                                                   uint_t* hbuf, float* __restrict__ out) {
  const int tid = threadIdx.x;
  const int w = tid >> 6, l = tid & 63;
  const int m_ = l & 15, q = l >> 4;
  const int j = blockIdx.x;

  // bfrag[g][kk]: B[k][n], n = g*512 + j*16 + m_, k = w*128 + kk*32 + q*8 + jj
  short8 bfrag[4][4];
  for (int g = 0; g < 4; g++) {
    const ushort_t* wrow = whh + (size_t)(g * HID + j * 16 + m_) * HID + w * 128 + q * 8;
    for (int kk = 0; kk < 4; kk++) bfrag[g][kk] = *(const short8*)(wrow + kk * 32);
  }

  const int erow = tid >> 4, ecol = tid & 15;  // epilogue ownership (batch row, h col)
  float c_reg = 0.f;
  __shared__ __align__(16) ushort_t hsm[BATCH * HID];   // 16 KB, XOR-swizzled chunks
  __shared__ float gsm[2][4][4][16][17];                // [par][wave][gate][row][col]

  // epilogue xg: idx(t,g) = (t*16 + erow)*2048 + g*512 + j*16 + ecol
  const ushort_t* xgp = xg + (size_t)erow * G4 + j * 16 + ecol;
  ushort_t xgv[4];
  for (int g = 0; g < 4; g++) xgv[g] = xgp[g * HID];

  // stage: wave w loads tagged cols [128w,128w+128) of all 16 rows.
  // instr r: lane l loads 8B (2 tagged u32) at u32 idx r*512 + w*128 + 2l.
  const ull_t* hb_ull = (const ull_t*)hbuf;   // ull idx = u32 idx / 2
  const int sbase = w * 64 + l;               // + r*256 per row, + buf*4096

  for (int t = 0; t < T_STEPS; t++) {
    // prefetch next step's xg (plain cached loads, independent of h)
    ushort_t xgn[4];
    {
      int tt = (t + 1 < T_STEPS) ? (t + 1) : t;
      const ushort_t* p = xgp + (size_t)tt * 16 * G4;
      for (int g = 0; g < 4; g++) xgn[g] = p[g * HID];
    }
    // ---- poll + load own slice (tags == t) ----
    ull_t vals[16];
    {
      const ull_t* gp = hb_ull + (size_t)(t & 1) * 4096 + sbase;
      const ull_t expect = ((ull_t)(uint_t)(t & 0xffff) << 16) |
                           ((ull_t)(uint_t)(t & 0xffff) << 48);
      for (;;) {
        for (int r = 0; r < 16; r++) vals[r] = cload64(gp + r * 256);
        bool ok = true;
        for (int r = 0; r < 16; r++)
          ok &= ((vals[r] & 0xFFFF0000FFFF0000ull) == expect);
        if (__all((int)ok)) break;
      }
    }
    // ---- strip tags, write own hsm slice (intra-wave only) ----
    // value pair = cols (128w + 2l, +1) of row r; chunk = 16w + (l>>2),
    // slot = chunk ^ (r&7), u32 offset (l&3) within 16B slot. Conflict-free.
    {
      const int chunk = w * 16 + (l >> 2);
      for (int r = 0; r < 16; r++) {
        uint_t pk = (uint_t)(vals[r] & 0xffffu) | ((uint_t)(vals[r] >> 32) << 16);
        int slot = chunk ^ (r & 7);
        *(uint_t*)(hsm + (size_t)r * HID + slot * 8 + (l & 3) * 2) = pk;
      }
    }
    // ---- MFMA: A row m_, chunks 16w + kk*4 + q (own slice; in-wave ordering) ----
    floatx4 acc[4];
    for (int g = 0; g < 4; g++) acc[g] = (floatx4){0.f, 0.f, 0.f, 0.f};
    for (int kk = 0; kk < 4; kk++) {
      int slot = (w * 16 + kk * 4 + q) ^ (m_ & 7);
      short8 a = *(const short8*)(hsm + (size_t)m_ * HID + slot * 8);
      for (int g = 0; g < 4; g++) acc[g] = mfma16(a, bfrag[g][kk], acc[g]);
    }
    // ---- partial exchange ----
    const int par = t & 1;
    for (int g = 0; g < 4; g++)
      for (int r = 0; r < 4; r++) gsm[par][w][g][q * 4 + r][m_] = acc[g][r];
    __syncthreads();

    float gate[4];
    for (int g = 0; g < 4; g++) {
      float s = gsm[par][0][g][erow][ecol] + gsm[par][1][g][erow][ecol] +
                gsm[par][2][g][erow][ecol] + gsm[par][3][g][erow][ecol];
      gate[g] = s + bf2f(xgv[g]);
    }
    float iv = sigf(gate[0]);
    float fv = sigf(gate[1]);
    float gv = tanhf_fast(gate[2]);
    float ov = sigf(gate[3]);
    float c = fv * c_reg + iv * gv;
    c_reg = c;
    float h = ov * tanhf_fast(c);

    // ---- publish tagged h(t+1): store and go (no drain, no flag) ----
    cstore32(hbuf + (size_t)((t + 1) & 1) * 8192 + (size_t)erow * HID + j * 16 + ecol,
             ((uint_t)((t + 1) & 0xffff) << 16) | (uint_t)f2bf(h));

    // off the critical path
    out[(size_t)erow * (T_STEPS * HID) + (size_t)t * HID + j * 16 + ecol] = h;
    for (int g = 0; g < 4; g++) xgv[g] = xgn[g];
  }
}

// ---------------- host ----------------
extern "C" void kernel_launch(void* const* d_in, const int* in_sizes, int n_in,
                              void* d_out, int out_size, void* d_ws, size_t ws_size,
                              hipStream_t stream) {
  (void)in_sizes; (void)n_in; (void)out_size;
  if (ws_size < WS_NEED) return;

  const float* x   = (const float*)d_in[0];
  const float* wih = (const float*)d_in[1];
  const float* whh = (const float*)d_in[2];
  const float* bih = (const float*)d_in[3];
  const float* bhh = (const float*)d_in[4];
  float* out = (float*)d_out;
  char* ws = (char*)d_ws;

  ushort_t* xg_b   = (ushort_t*)(ws + XG_OFF);
  ushort_t* xT_b   = (ushort_t*)(ws + XT_OFF);
  ushort_t* wih_b  = (ushort_t*)(ws + WIH_OFF);
  ushort_t* whh_b  = (ushort_t*)(ws + WHH_OFF);
  uint_t*   hbuf   = (uint_t*)(ws + HBUF_OFF);

  // zero tagged h double-buffer: tag 0 == h(0) == 0 (ws poisoned 0xAA each call)
  hipMemsetAsync(ws + HBUF_OFF, 0, 65536, stream);

  conv_x_k<<<24576, 256, 0, stream>>>((const float4*)x, xT_b);
  conv_w_k<<<1536, 256, 0, stream>>>((const float4*)wih, wih_b, 393216u);
  conv_w_k<<<1024, 256, 0, stream>>>((const float4*)whh, whh_b, 262144u);
  gemm_xg<<<dim3(16, 256), 256, 0, stream>>>(xT_b, wih_b, bih, bhh, xg_b);
  lstm_rec<<<NBLK, 256, 0, stream>>>(xg_b, whh_b, hbuf, out);
}